// Round 1
// baseline (330.998 us; speedup 1.0000x reference)
//
#include <hip/hip_runtime.h>
#include <math.h>

// Problem constants (from reference setup_inputs)
#define N_SAMPLES 131072
#define DIM 256
#define C_CLASSES 100
#define K_BALLS 2
#define M_BALLS (C_CLASSES * K_BALLS)   // 200
#define TAU_B 0.5f
#define MARGIN_M 0.5f
#define ETA 1.0f
#define LAM_IN 1.0
#define LAM_OV 1.0
#define LAM_DIV 0.5

// ws layout: ws[0] = intra sum, ws[1] = overlap sum, ws[2] = diversity sum (doubles)

__global__ void zero_ws_kernel(double* ws) {
    int t = threadIdx.x;
    if (t < 3) ws[t] = 0.0;
}

// One wave (64 lanes) per sample; lane l owns z[n, 4l..4l+3].
__global__ __launch_bounds__(256) void intra_kernel(
    const float* __restrict__ z,
    const int* __restrict__ labels,
    const float* __restrict__ centers,   // [C, K, D]
    const float* __restrict__ radii_raw, // [C, K]
    double* __restrict__ ws)
{
    const int lane = threadIdx.x & 63;
    const int wave = threadIdx.x >> 6;
    const int gwave = blockIdx.x * (blockDim.x >> 6) + wave;
    const int nwaves = gridDim.x * (blockDim.x >> 6);

    float acc = 0.0f;

    for (int n = gwave; n < N_SAMPLES; n += nwaves) {
        const int lbl = labels[n];
        const float4 zv = *reinterpret_cast<const float4*>(z + (size_t)n * DIM + 4 * lane);
        const float* cbase = centers + (size_t)lbl * (K_BALLS * DIM);
        const float4 c0 = *reinterpret_cast<const float4*>(cbase + 4 * lane);
        const float4 c1 = *reinterpret_cast<const float4*>(cbase + DIM + 4 * lane);

        float t;
        float d0 = 0.0f, d1 = 0.0f;
        t = zv.x - c0.x; d0 = fmaf(t, t, d0);
        t = zv.y - c0.y; d0 = fmaf(t, t, d0);
        t = zv.z - c0.z; d0 = fmaf(t, t, d0);
        t = zv.w - c0.w; d0 = fmaf(t, t, d0);
        t = zv.x - c1.x; d1 = fmaf(t, t, d1);
        t = zv.y - c1.y; d1 = fmaf(t, t, d1);
        t = zv.z - c1.z; d1 = fmaf(t, t, d1);
        t = zv.w - c1.w; d1 = fmaf(t, t, d1);

        // wave (64-lane) reduction
        #pragma unroll
        for (int off = 32; off > 0; off >>= 1) {
            d0 += __shfl_down(d0, off, 64);
            d1 += __shfl_down(d1, off, 64);
        }

        if (lane == 0) {
            const float r0 = fabsf(radii_raw[lbl * K_BALLS + 0]) + 1e-6f;
            const float r1 = fabsf(radii_raw[lbl * K_BALLS + 1]) + 1e-6f;
            // stable softmax over K=2 of (-d/tau)
            const float a0 = -d0 / TAU_B;
            const float a1 = -d1 / TAU_B;
            const float m = fmaxf(a0, a1);
            const float e0 = expf(a0 - m);
            const float e1 = expf(a1 - m);
            const float inv = 1.0f / (e0 + e1);
            const float q0 = e0 * inv;
            const float q1 = e1 * inv;
            const float dsw = q0 * d0 + q1 * d1;
            const float rsw = q0 * r0 * r0 + q1 * r1 * r1;
            acc += fmaxf(dsw - ETA * rsw, 0.0f);
        }
    }

    if (lane == 0) atomicAdd(&ws[0], (double)acc);
}

// Block i handles ball row i; 4 waves stride over j. Diversity pair folded in.
__global__ __launch_bounds__(256) void pair_kernel(
    const float* __restrict__ centers,   // flat [M, D]
    const float* __restrict__ radii_raw, // flat [M]
    double* __restrict__ ws)
{
    __shared__ float rfl[M_BALLS];
    const int i = blockIdx.x;
    const int lane = threadIdx.x & 63;
    const int wave = threadIdx.x >> 6;

    for (int t = threadIdx.x; t < M_BALLS; t += blockDim.x)
        rfl[t] = fabsf(radii_raw[t]) + 1e-6f;
    __syncthreads();

    // lane's fixed slice of c_i
    const float4 civ = *reinterpret_cast<const float4*>(centers + (size_t)i * DIM + 4 * lane);

    float ov_acc = 0.0f;
    float div_acc = 0.0f;

    for (int j = wave; j < M_BALLS; j += 4) {
        const float4 cjv = *reinterpret_cast<const float4*>(centers + (size_t)j * DIM + 4 * lane);
        float t, s = 0.0f;
        t = civ.x - cjv.x; s = fmaf(t, t, s);
        t = civ.y - cjv.y; s = fmaf(t, t, s);
        t = civ.z - cjv.z; s = fmaf(t, t, s);
        t = civ.w - cjv.w; s = fmaf(t, t, s);
        #pragma unroll
        for (int off = 32; off > 0; off >>= 1)
            s += __shfl_down(s, off, 64);
        if (lane == 0 && j != i) {
            const float d = sqrtf(s);
            ov_acc += fmaxf(rfl[i] + rfl[j] + MARGIN_M - d, 0.0f);
            // diversity: same class means balls (2c, 2c+1); count once (i even, j = i+1)
            if ((i & 1) == 0 && j == i + 1)
                div_acc += fmaxf(1.0f - d, 0.0f);
        }
    }

    if (lane == 0) {
        atomicAdd(&ws[1], (double)ov_acc);
        atomicAdd(&ws[2], (double)div_acc);
    }
}

__global__ void finalize_kernel(const double* __restrict__ ws, float* __restrict__ out) {
    const double L_intra = ws[0] / (double)N_SAMPLES;
    const double L_overlap = ws[1] / (double)(M_BALLS * (M_BALLS - 1)); // 39800
    const double L_div = ws[2] / (double)(C_CLASSES * K_BALLS * (K_BALLS - 1) / 2); // 100
    const double total = LAM_IN * L_intra + LAM_OV * L_overlap + LAM_DIV * L_div;
    out[0] = (float)total;
    out[1] = (float)L_intra;
    out[2] = (float)L_overlap;
    out[3] = (float)L_div;
}

extern "C" void kernel_launch(void* const* d_in, const int* in_sizes, int n_in,
                              void* d_out, int out_size, void* d_ws, size_t ws_size,
                              hipStream_t stream) {
    const float* z = (const float*)d_in[0];
    const int* labels = (const int*)d_in[1];
    const float* centers = (const float*)d_in[2];
    const float* radii = (const float*)d_in[3];
    float* out = (float*)d_out;
    double* ws = (double*)d_ws;

    zero_ws_kernel<<<1, 64, 0, stream>>>(ws);
    // 2048 blocks x 256 threads = 8192 waves, 16 samples each
    intra_kernel<<<2048, 256, 0, stream>>>(z, labels, centers, radii, ws);
    pair_kernel<<<M_BALLS, 256, 0, stream>>>(centers, radii, ws);
    finalize_kernel<<<1, 1, 0, stream>>>(ws, out);
}

// Round 2
// 203.008 us; speedup vs baseline: 1.6305x; 1.6305x over previous
//
#include <hip/hip_runtime.h>
#include <math.h>

// Problem constants (from reference setup_inputs)
#define N_SAMPLES 131072
#define DIM 256
#define C_CLASSES 100
#define K_BALLS 2
#define M_BALLS 200          // C*K
#define TAU_B 0.5f
#define MARGIN_M 0.5f

// ws layout (doubles): 8 slots per term, 16-double (128B) stride to avoid
// same-cacheline atomic contention.
#define SLOT_STRIDE 16
#define WS_INTRA 0
#define WS_OV 128
#define WS_DV 256
#define WS_TOTAL 384  // doubles = 3 KB

__global__ void zero_ws_kernel(double* ws) {
    const int t = blockIdx.x * blockDim.x + threadIdx.x;
    if (t < WS_TOTAL) ws[t] = 0.0;
}

__device__ __forceinline__ void acc_sq(const float4 x, const float4 y, float& d) {
    float t;
    t = x.x - y.x; d = fmaf(t, t, d);
    t = x.y - y.y; d = fmaf(t, t, d);
    t = x.z - y.z; d = fmaf(t, t, d);
    t = x.w - y.w; d = fmaf(t, t, d);
}

// 4 samples per wave: 16-lane group per sample, lane owns 16 floats (4x float4).
// 2048 blocks x 256 threads = 8192 waves x 16 samples = 131072.
__global__ __launch_bounds__(256, 4) void intra_kernel(
    const float* __restrict__ z,
    const int* __restrict__ labels,
    const float* __restrict__ centers,   // [C, K, D]
    const float* __restrict__ radii_raw, // [C, K]
    double* __restrict__ ws)
{
    __shared__ float wsum[4];
    const int lane = threadIdx.x & 63;
    const int wv = threadIdx.x >> 6;
    const int gwave = (blockIdx.x * blockDim.x + threadIdx.x) >> 6;
    const int grp = lane >> 4;   // which of 4 samples in this wave-iteration
    const int sl = lane & 15;    // lane within the 16-lane sample group
    const int base = gwave * 16; // this wave's 16 contiguous samples

    // lanes 0-15 hold the wave's 16 labels (dup x4 across groups), one coalesced load
    const int lab = labels[base + sl];

    float acc = 0.0f;

    for (int it = 0; it < 4; ++it) {
        const int n = base + it * 4 + grp;
        const int lbl = __shfl(lab, it * 4 + grp, 64);

        const float* zp = z + (size_t)n * DIM + sl * 4;
        const float* cp = centers + (size_t)lbl * (2 * DIM) + sl * 4;

        // 12 independent float4 loads: z row slice + both ball-center slices
        const float4 z0 = *(const float4*)(zp);
        const float4 z1 = *(const float4*)(zp + 64);
        const float4 z2 = *(const float4*)(zp + 128);
        const float4 z3 = *(const float4*)(zp + 192);
        const float4 a0 = *(const float4*)(cp);
        const float4 a1 = *(const float4*)(cp + 64);
        const float4 a2 = *(const float4*)(cp + 128);
        const float4 a3 = *(const float4*)(cp + 192);
        const float4 b0 = *(const float4*)(cp + 256);
        const float4 b1 = *(const float4*)(cp + 320);
        const float4 b2 = *(const float4*)(cp + 384);
        const float4 b3 = *(const float4*)(cp + 448);

        float d0 = 0.0f, d1 = 0.0f;
        acc_sq(z0, a0, d0); acc_sq(z1, a1, d0); acc_sq(z2, a2, d0); acc_sq(z3, a3, d0);
        acc_sq(z0, b0, d1); acc_sq(z1, b1, d1); acc_sq(z2, b2, d1); acc_sq(z3, b3, d1);

        // 4-level butterfly within each 16-lane group (all 4 samples at once)
        #pragma unroll
        for (int m = 1; m <= 8; m <<= 1) {
            d0 += __shfl_xor(d0, m, 64);
            d1 += __shfl_xor(d1, m, 64);
        }

        if (sl == 0) {
            const float r0 = fabsf(radii_raw[lbl * 2 + 0]) + 1e-6f;
            const float r1 = fabsf(radii_raw[lbl * 2 + 1]) + 1e-6f;
            // stable softmax over K=2 of -d/tau  (1/TAU_B = 2)
            const float s0 = -d0 * 2.0f;
            const float s1 = -d1 * 2.0f;
            const float mx = fmaxf(s0, s1);
            const float e0 = expf(s0 - mx);
            const float e1 = expf(s1 - mx);
            const float inv = 1.0f / (e0 + e1);
            const float q0 = e0 * inv, q1 = e1 * inv;
            const float dsw = q0 * d0 + q1 * d1;
            const float rsw = q0 * r0 * r0 + q1 * r1 * r1;  // ETA = 1
            acc += fmaxf(dsw - rsw, 0.0f);
        }
    }

    // combine the 4 group-leader lanes (0,16,32,48); others hold 0
    acc += __shfl_xor(acc, 16, 64);
    acc += __shfl_xor(acc, 32, 64);
    if (lane == 0) wsum[wv] = acc;
    __syncthreads();
    if (threadIdx.x == 0) {
        const float s = wsum[0] + wsum[1] + wsum[2] + wsum[3];
        atomicAdd(&ws[WS_INTRA + (blockIdx.x & 7) * SLOT_STRIDE], (double)s);
    }
}

// Fully parallel pairs: block (i, j-chunk of 16); each wave handles 4 j's
// in 16-lane groups. grid = (200, 13).
__global__ __launch_bounds__(256) void pair_kernel(
    const float* __restrict__ centers,   // flat [M, D]
    const float* __restrict__ radii_raw, // flat [M]
    double* __restrict__ ws)
{
    __shared__ float s_ov[4], s_dv[4];
    const int lane = threadIdx.x & 63;
    const int wv = threadIdx.x >> 6;
    const int grp = lane >> 4;
    const int sl = lane & 15;
    const int i = blockIdx.x;
    const int j = blockIdx.y * 16 + wv * 4 + grp;
    const int jc = j < M_BALLS ? j : M_BALLS - 1;  // clamp address, mask result

    const float* ip = centers + (size_t)i * DIM + sl * 4;
    const float* jp = centers + (size_t)jc * DIM + sl * 4;

    const float4 i0 = *(const float4*)(ip);
    const float4 i1 = *(const float4*)(ip + 64);
    const float4 i2 = *(const float4*)(ip + 128);
    const float4 i3 = *(const float4*)(ip + 192);
    const float4 j0 = *(const float4*)(jp);
    const float4 j1 = *(const float4*)(jp + 64);
    const float4 j2 = *(const float4*)(jp + 128);
    const float4 j3 = *(const float4*)(jp + 192);

    float s = 0.0f;
    acc_sq(i0, j0, s); acc_sq(i1, j1, s); acc_sq(i2, j2, s); acc_sq(i3, j3, s);

    #pragma unroll
    for (int m = 1; m <= 8; m <<= 1)
        s += __shfl_xor(s, m, 64);

    float ov = 0.0f, dv = 0.0f;
    if (sl == 0 && j < M_BALLS && j != i) {
        const float d = sqrtf(s);
        const float ri = fabsf(radii_raw[i]) + 1e-6f;
        const float rj = fabsf(radii_raw[j]) + 1e-6f;
        ov = fmaxf(ri + rj + MARGIN_M - d, 0.0f);
        // diversity: within-class pair p<q == (even i, j==i+1); count once
        if (((i & 1) == 0) && (j == i + 1))
            dv = fmaxf(1.0f - d, 0.0f);
    }
    ov += __shfl_xor(ov, 16, 64);
    ov += __shfl_xor(ov, 32, 64);
    dv += __shfl_xor(dv, 16, 64);
    dv += __shfl_xor(dv, 32, 64);

    if (lane == 0) { s_ov[wv] = ov; s_dv[wv] = dv; }
    __syncthreads();
    if (threadIdx.x == 0) {
        const float o = s_ov[0] + s_ov[1] + s_ov[2] + s_ov[3];
        const float d2 = s_dv[0] + s_dv[1] + s_dv[2] + s_dv[3];
        const int slot = (blockIdx.x & 7) * SLOT_STRIDE;
        if (o != 0.0f) atomicAdd(&ws[WS_OV + slot], (double)o);
        if (d2 != 0.0f) atomicAdd(&ws[WS_DV + slot], (double)d2);
    }
}

__global__ void finalize_kernel(const double* __restrict__ ws, float* __restrict__ out) {
    double si = 0.0, so = 0.0, sd = 0.0;
    for (int s = 0; s < 8; ++s) {
        si += ws[WS_INTRA + s * SLOT_STRIDE];
        so += ws[WS_OV + s * SLOT_STRIDE];
        sd += ws[WS_DV + s * SLOT_STRIDE];
    }
    const double L_intra = si / (double)N_SAMPLES;
    const double L_overlap = so / (double)(M_BALLS * (M_BALLS - 1));       // 39800
    const double L_div = sd / (double)(C_CLASSES * K_BALLS * (K_BALLS - 1) / 2); // 100
    const double total = L_intra + L_overlap + 0.5 * L_div;
    out[0] = (float)total;
    out[1] = (float)L_intra;
    out[2] = (float)L_overlap;
    out[3] = (float)L_div;
}

extern "C" void kernel_launch(void* const* d_in, const int* in_sizes, int n_in,
                              void* d_out, int out_size, void* d_ws, size_t ws_size,
                              hipStream_t stream) {
    const float* z = (const float*)d_in[0];
    const int* labels = (const int*)d_in[1];
    const float* centers = (const float*)d_in[2];
    const float* radii = (const float*)d_in[3];
    float* out = (float*)d_out;
    double* ws = (double*)d_ws;

    zero_ws_kernel<<<2, 256, 0, stream>>>(ws);
    intra_kernel<<<2048, 256, 0, stream>>>(z, labels, centers, radii, ws);
    pair_kernel<<<dim3(200, 13), 256, 0, stream>>>(centers, radii, ws);
    finalize_kernel<<<1, 1, 0, stream>>>(ws, out);
}